// Round 11
// baseline (252.640 us; speedup 1.0000x reference)
//
#include <hip/hip_runtime.h>

typedef _Float16 h16_t;
typedef _Float16 half8 __attribute__((ext_vector_type(8)));
typedef _Float16 half4v __attribute__((ext_vector_type(4)));
typedef float f32x4 __attribute__((ext_vector_type(4)));

#define SEQ 2048
#define DM 2048
#define NHEAD 16
#define HDIM 128
#define QKVW 6144
#define QKW 4096

#define GLOAD_LDS(g, l)                                                   \
  __builtin_amdgcn_global_load_lds(                                       \
      (const __attribute__((address_space(1))) void*)(g),                 \
      (__attribute__((address_space(3))) void*)(l), 16, 0, 0)

#define VMCNT(n) asm volatile("s_waitcnt vmcnt(" #n ")" ::: "memory")

// ---------------- fp32 -> (hi,lo) fp16 split ----------------
__global__ void cvt_split(const float* __restrict__ src, h16_t* __restrict__ hi,
                          h16_t* __restrict__ lo, int n4) {
  int i = blockIdx.x * blockDim.x + threadIdx.x;
  if (i < n4) {
    float4 v = reinterpret_cast<const float4*>(src)[i];
    half4v h, l;
    float x;
    x = v.x; h[0] = (h16_t)x; l[0] = (h16_t)(x - (float)h[0]);
    x = v.y; h[1] = (h16_t)x; l[1] = (h16_t)(x - (float)h[1]);
    x = v.z; h[2] = (h16_t)x; l[2] = (h16_t)(x - (float)h[2]);
    x = v.w; h[3] = (h16_t)x; l[3] = (h16_t)(x - (float)h[3]);
    reinterpret_cast<half4v*>(hi)[i] = h;
    reinterpret_cast<half4v*>(lo)[i] = l;
  }
}

// ------- fp32 W[K][N] -> fp16 Wt[N][K] (hi only), vectorized ----------------
__global__ void transpose_f16(const float* __restrict__ W, h16_t* __restrict__ Wt,
                              int K, int N) {
  __shared__ float tile[64][65];
  int n0 = blockIdx.x * 64, k0 = blockIdx.y * 64;
  int t = threadIdx.x;  // 256
  int row = t >> 4, c4 = t & 15;
#pragma unroll
  for (int j = 0; j < 4; ++j) {
    float4 v = *reinterpret_cast<const float4*>(
        &W[(size_t)(k0 + j * 16 + row) * N + n0 + c4 * 4]);
    tile[j * 16 + row][c4 * 4 + 0] = v.x;
    tile[j * 16 + row][c4 * 4 + 1] = v.y;
    tile[j * 16 + row][c4 * 4 + 2] = v.z;
    tile[j * 16 + row][c4 * 4 + 3] = v.w;
  }
  __syncthreads();
#pragma unroll
  for (int jj = 0; jj < 2; ++jj) {
    int idx = jj * 256 + t;
    int n = idx >> 3, kc = idx & 7;
    half8 hv;
#pragma unroll
    for (int e = 0; e < 8; ++e) hv[e] = (h16_t)tile[kc * 8 + e][n];
    *reinterpret_cast<half8*>(&Wt[(size_t)(n0 + n) * K + k0 + kc * 8]) = hv;
  }
}

// ---------------- cos/sin table [SEQ][64] fp32 ----------------
__global__ void ctab_kernel(float2* __restrict__ tab) {
  int idx = blockIdx.x * blockDim.x + threadIdx.x;  // 2048*64
  int s = idx >> 6, i = idx & 63;
  float freq = 1.0f / powf(10000.0f, (float)(2 * i) / 128.0f);
  float ang = (float)s * freq;
  float sn, cs;
  sincosf(ang, &sn, &cs);
  tab[idx] = make_float2(cs, sn);
}

// ---------------- GEMM body: C[M][N] = A[M][K]*Bt[N][K]^T + bias -----------
// 128x128 tile, BK=32, 4 waves (2x2). R5 schedule (verified):
//   stage(next) | ds_reads | MFMA (setprio) | VMCNT0 | syncthreads.
// ASPLIT: 2-product (Ahi+Alo)*Bhi — removes A-rounding error, keeps W error.
// OUT: 0 = fp16 hi, 1 = fp16 hi+lo, 2 = fp32.
// ROPE: rotate output pairs in-register (tile spans one head) + hi/lo split.
// BROW: bias indexed by output row instead of column.
template <int ASPLIT, int OUT, int ROPE, int BROW>
__device__ __forceinline__ void gemm_body(
    char* smem,
    const h16_t* __restrict__ Ahi, const h16_t* __restrict__ Alo,
    const h16_t* __restrict__ Bhi,
    const float* __restrict__ bias, void* __restrict__ Cout,
    h16_t* __restrict__ Clo, int brow, int bcol, int ldc, int K, int ldlo,
    int tid, const float2* __restrict__ tab) {
  constexpr int BUF = ASPLIT ? 24576 : 16384;
  const int w = tid >> 6, lane = tid & 63, c = lane & 15, g = lane >> 4;
  const int wr = (w >> 1) * 64, wc = (w & 1) * 64;

  f32x4 acc[4][4] = {};

  // stage K-step k0 into buffer bufi (linear dest, inverse-swizzled source)
  auto stage = [&](int bufi, int k0) {
    char* buf = smem + bufi * BUF;
#pragma unroll
    for (int it = 0; it < 2; ++it) {
      int B = it * 256 + tid;
      int row = B >> 2;
      int c8 = (B & 3) ^ ((row >> 1) & 3);
      int loff = it * 4096 + w * 1024;
      GLOAD_LDS(Ahi + (size_t)(brow + row) * K + k0 + c8 * 8, buf + loff);
      GLOAD_LDS(Bhi + (size_t)(bcol + row) * K + k0 + c8 * 8, buf + 8192 + loff);
      if (ASPLIT)
        GLOAD_LDS(Alo + (size_t)(brow + row) * K + k0 + c8 * 8, buf + 16384 + loff);
    }
  };

  int cur = 0;
  stage(0, 0);
  VMCNT(0);
  __syncthreads();

#pragma unroll 1
  for (int k0 = 0; k0 < K; k0 += 32) {
    if (k0 + 32 < K) stage(cur ^ 1, k0 + 32);
    const char* bufc = smem + cur * BUF;
    half8 afh[4], bfh[4], afl[4];
#pragma unroll
    for (int f = 0; f < 4; ++f) {
      int rowa = wr + f * 16 + c;
      int offa = rowa * 64 + ((g ^ ((rowa >> 1) & 3)) * 16);
      int rowb = wc + f * 16 + c;
      int offb = rowb * 64 + ((g ^ ((rowb >> 1) & 3)) * 16);
      afh[f] = *reinterpret_cast<const half8*>(bufc + offa);
      bfh[f] = *reinterpret_cast<const half8*>(bufc + 8192 + offb);
      if (ASPLIT) afl[f] = *reinterpret_cast<const half8*>(bufc + 16384 + offa);
    }
    __builtin_amdgcn_s_setprio(1);
#pragma unroll
    for (int fm = 0; fm < 4; ++fm)
#pragma unroll
      for (int fn = 0; fn < 4; ++fn) {
        acc[fm][fn] = __builtin_amdgcn_mfma_f32_16x16x32_f16(afh[fm], bfh[fn], acc[fm][fn], 0, 0, 0);
        if (ASPLIT)
          acc[fm][fn] = __builtin_amdgcn_mfma_f32_16x16x32_f16(afl[fm], bfh[fn], acc[fm][fn], 0, 0, 0);
      }
    __builtin_amdgcn_s_setprio(0);
    VMCNT(0);
    __syncthreads();
    cur ^= 1;
  }

  const float fac = (ROPE && bcol < 2048) ? 11.31370849898476f : 1.0f;
#pragma unroll
  for (int fm = 0; fm < 4; ++fm)
#pragma unroll
    for (int fn = 0; fn < 4; ++fn) {
      int col = bcol + wc + fn * 16 + c;
      float bv = BROW ? 0.f : bias[col];
#pragma unroll
      for (int r = 0; r < 4; ++r) {
        int row = brow + wr + fm * 16 + 4 * g + r;
        float v = acc[fm][fn][r] + (BROW ? bias[row] : bv);
        if (ROPE) {
          // pair (2i,2i+1) sits on adjacent lanes (c even/odd)
          float pv = __shfl_xor(v, 1);
          float2 cc = tab[row * 64 + ((col & 127) >> 1)];
          float y = (col & 1) ? (v * cc.x + pv * cc.y) * fac
                              : (v * cc.x - pv * cc.y) * fac;
          h16_t hv = (h16_t)y;
          ((h16_t*)Cout)[(size_t)row * ldc + col] = hv;
          Clo[(size_t)row * ldlo + col] = (h16_t)(y - (float)hv);
        } else if (OUT == 2) {
          ((float*)Cout)[(size_t)row * ldc + col] = v;
        } else {
          h16_t hv = (h16_t)v;
          ((h16_t*)Cout)[(size_t)row * ldc + col] = hv;
          if (OUT == 1) Clo[(size_t)row * ldlo + col] = (h16_t)(v - (float)hv);
        }
      }
    }
}

// ---------------- q,k columns: 2-product A-split GEMM + fused RoPE ----------
__global__ __launch_bounds__(256) void gemm_qk(
    const h16_t* __restrict__ h_hi, const h16_t* __restrict__ h_lo,
    const h16_t* __restrict__ qkvT_hi, const float* __restrict__ bqkv,
    h16_t* __restrict__ qk_hi, h16_t* __restrict__ qk_lo,
    const float2* __restrict__ tab) {
  __shared__ __align__(16) char smem[49152];
  gemm_body<1, 1, 1, 0>(smem, h_hi, h_lo, qkvT_hi, bqkv, qk_hi, qk_lo,
                        blockIdx.y * 128, blockIdx.x * 128, QKW, DM, QKW,
                        threadIdx.x, tab);
}

// ---------------- v columns -> Vt[vc][s] directly (operands swapped) --------
__global__ __launch_bounds__(256) void gemm_v(
    const h16_t* __restrict__ wvT_hi, const h16_t* __restrict__ h_hi,
    const float* __restrict__ bias_v, h16_t* __restrict__ vt) {
  __shared__ __align__(16) char smem[32768];
  gemm_body<0, 0, 0, 1>(smem, wvT_hi, nullptr, h_hi, bias_v, vt,
                        nullptr, blockIdx.y * 128, blockIdx.x * 128, SEQ, DM, 0,
                        threadIdx.x, nullptr);
}

// ---------------- out-projection GEMM (fp32 out) ----------------
__global__ __launch_bounds__(256) void gemm_oproj(
    const h16_t* __restrict__ A, const h16_t* __restrict__ Bt,
    const float* __restrict__ bias, float* __restrict__ Cout) {
  __shared__ __align__(16) char smem[32768];
  gemm_body<0, 2, 0, 0>(smem, A, nullptr, Bt, bias, Cout, nullptr,
                        blockIdx.y * 128, blockIdx.x * 128, DM, DM, 0,
                        threadIdx.x, nullptr);
}

// ---------------- causal flash attention, split-K, 2-buf + 3 blocks/CU ------
// 768 blocks: h = p&15 (XCD-pinned), cq = p>>4:
//   cq<16 : qb=16+cq, keys [0,1024)            -> partial chunk 0
//   cq<32 : qb=47-cq, keys [1024,(qb+1)*64)    -> partial chunk 1
//   else  : qb=47-cq (15..0), all keys         -> direct ctx write
// 2-buffer pipeline (48KB LDS -> 3 blocks/CU): top-of-iter vmcnt(0) waits
// stage(i) (issued one full compute-phase ago) -> raw s_barrier -> issue
// stage(i+1) -> compute. Per-lane deferred denominator; hoisted causal mask.
__global__ __launch_bounds__(256) void attn_kernel(const h16_t* __restrict__ qhi,
                                                   const h16_t* __restrict__ qlo,
                                                   const h16_t* __restrict__ vt,
                                                   h16_t* __restrict__ ctx,
                                                   float* __restrict__ Opart,
                                                   float* __restrict__ ms) {
  __shared__ __align__(16) char smem[2 * 24576];
  const int tid = threadIdx.x, w = tid >> 6, lane = tid & 63, c = lane & 15, g = lane >> 4;
  const int p = blockIdx.x;
  const int h = p & 15;
  const int cq = p >> 4;
  int qb, t0, nt, pidx;
  if (cq < 16)      { qb = 16 + cq; t0 = 0;  nt = 32;          pidx = h * 32 + cq * 2; }
  else if (cq < 32) { qb = 47 - cq; t0 = 32; nt = 2 * qb - 30; pidx = h * 32 + (qb - 16) * 2 + 1; }
  else              { qb = 47 - cq; t0 = 0;  nt = 2 * qb + 2;  pidx = -1; }

  const h16_t* Kph = qhi + 2048 + h * HDIM;
  const h16_t* Kpl = qlo + 2048 + h * HDIM;
  const h16_t* Vth = vt + (size_t)h * HDIM * SEQ;
  const float L2E = 1.4426950408889634f;

  const int q0 = qb * 64;
  const int qw = q0 + w * 16;

  // stage one KVBLK=32 tile (Khi, Klo row-major swizzled; Vt [128 d][32 key])
  auto stage = [&](int bufi, int t) {
    char* buf = smem + bufi * 24576;
    const int k0 = t * 32;
#pragma unroll
    for (int it = 0; it < 2; ++it) {
      int B = it * 256 + tid;
      int loff = it * 4096 + w * 1024;
      int row = B >> 4;                       // key row 0..31
      int c16 = (B & 15) ^ (row & 7);
      GLOAD_LDS(Kph + (size_t)(k0 + row) * QKW + c16 * 8, buf + loff);
      GLOAD_LDS(Kpl + (size_t)(k0 + row) * QKW + c16 * 8, buf + 8192 + loff);
      int rv = B >> 2;                        // d row 0..127
      int c4 = (B & 3) ^ ((rv >> 1) & 3);
      GLOAD_LDS(Vth + (size_t)rv * SEQ + k0 + c4 * 8, buf + 16384 + loff);
    }
  };

  half8 qfh[4], qfl[4];
#pragma unroll
  for (int kc = 0; kc < 4; ++kc) {
    qfh[kc] = *reinterpret_cast<const half8*>(qhi + (size_t)(qw + c) * QKW + h * HDIM + kc * 32 + g * 8);
    qfl[kc] = *reinterpret_cast<const half8*>(qlo + (size_t)(qw + c) * QKW + h * HDIM + kc * 32 + g * 8);
  }

  f32x4 oacc[8] = {};
  float m_run = -3.0e38f, s_part = 0.f;

  stage(0, t0);

#pragma unroll 1
  for (int i = 0; i < nt; ++i) {
    // stage(i) was issued one full compute-phase ago; nothing else in flight.
    VMCNT(0);
    __builtin_amdgcn_s_barrier();
    __builtin_amdgcn_sched_barrier(0);
    if (i + 1 < nt) stage((i + 1) & 1, t0 + i + 1);
    __builtin_amdgcn_sched_barrier(0);

    const int k0 = (t0 + i) * 32;
    const char* buf = smem + (i & 1) * 24576;
    const char* bufV = buf + 16384;

    // S^T = K * Q, 3-product split (32 keys x 16 q per wave)
    f32x4 st[2] = {};
    __builtin_amdgcn_s_setprio(1);
#pragma unroll
    for (int kc = 0; kc < 4; ++kc)
#pragma unroll
      for (int fm = 0; fm < 2; ++fm) {
        int row = fm * 16 + c;
        int so = row * 256 + (((4 * kc + g) ^ (row & 7)) * 16);
        half8 kfh = *reinterpret_cast<const half8*>(buf + so);
        half8 kfl = *reinterpret_cast<const half8*>(buf + 8192 + so);
        st[fm] = __builtin_amdgcn_mfma_f32_16x16x32_f16(kfh, qfh[kc], st[fm], 0, 0, 0);
        st[fm] = __builtin_amdgcn_mfma_f32_16x16x32_f16(kfh, qfl[kc], st[fm], 0, 0, 0);
        st[fm] = __builtin_amdgcn_mfma_f32_16x16x32_f16(kfl, qfh[kc], st[fm], 0, 0, 0);
      }
    __builtin_amdgcn_s_setprio(0);

    // causal mask (hoisted, wave-uniform) + online softmax (defer-max THR=8,
    // per-lane deferred denominator; scale pre-folded into q)
    float p_[2][4];
    float tmax = -3.0e38f;
    const int qg = qw + c;
    const bool needmask = (k0 + 31 > qw);
#pragma unroll
    for (int fm = 0; fm < 2; ++fm)
#pragma unroll
      for (int r = 0; r < 4; ++r) {
        float sf = st[fm][r];
        if (needmask) {
          int key = k0 + fm * 16 + 4 * g + r;
          sf = (key > qg) ? -3.0e38f : sf;
        }
        p_[fm][r] = sf;
        tmax = fmaxf(tmax, sf);
      }
    tmax = fmaxf(tmax, __shfl_xor(tmax, 16));
    tmax = fmaxf(tmax, __shfl_xor(tmax, 32));
    if (!__all(tmax - m_run <= 8.0f)) {
      float m_new = fmaxf(m_run, tmax);
      float alpha = exp2f((m_run - m_new) * L2E);
      float ar[4];
#pragma unroll
      for (int r = 0; r < 4; ++r) ar[r] = __shfl(alpha, 4 * g + r);
#pragma unroll
      for (int tt = 0; tt < 8; ++tt)
#pragma unroll
        for (int r = 0; r < 4; ++r) oacc[tt][r] *= ar[r];
      s_part *= alpha;
      m_run = m_new;
    }
#pragma unroll
    for (int fm = 0; fm < 2; ++fm)
#pragma unroll
      for (int r = 0; r < 4; ++r) {
        float e = exp2f((p_[fm][r] - m_run) * L2E);
        p_[fm][r] = e;
        s_part += e;
      }

    // pack P fragment: slot i <-> key 16*(i>>2) + 4g + (i&3)  (per-lane, free)
    half8 ap;
#pragma unroll
    for (int j = 0; j < 8; ++j) ap[j] = (h16_t)p_[j >> 2][j & 3];

    // PV: B-frag = two swizzled b64 reads of Vt (keys 4g..4g+3, 16+4g..16+4g+3)
    __builtin_amdgcn_s_setprio(1);
#pragma unroll
    for (int tt = 0; tt < 8; ++tt) {
      int row = 16 * tt + c;
      int sw = (row >> 1) & 3;
      int b1 = (g >> 1), b2 = 2 + (g >> 1);
      int a1 = row * 64 + (((b1 ^ sw)) * 16) + 8 * (g & 1);
      int a2 = row * 64 + (((b2 ^ sw)) * 16) + 8 * (g & 1);
      union { half8 v8; half4v v4[2]; } u;
      u.v4[0] = *reinterpret_cast<const half4v*>(bufV + a1);
      u.v4[1] = *reinterpret_cast<const half4v*>(bufV + a2);
      oacc[tt] = __builtin_amdgcn_mfma_f32_16x16x32_f16(ap, u.v8, oacc[tt], 0, 0, 0);
    }
    __builtin_amdgcn_s_setprio(0);
  }

  // final cross-lane denominator reduce (deferred from the loop)
  float s_run = s_part;
  s_run += __shfl_xor(s_run, 16);
  s_run += __shfl_xor(s_run, 32);

  if (pidx >= 0) {
    // partial: store fp32 O, m, s (consistent w.r.t. m_run reference point)
    float* Od = Opart + (size_t)pidx * 8192;
#pragma unroll
    for (int tt = 0; tt < 8; ++tt)
#pragma unroll
      for (int r = 0; r < 4; ++r)
        Od[(w * 16 + 4 * g + r) * 128 + tt * 16 + c] = oacc[tt][r];
    if (lane < 16) {
      ms[pidx * 128 + w * 16 + c] = m_run;
      ms[pidx * 128 + 64 + w * 16 + c] = s_run;
    }
  } else {
    float sr[4];
#pragma unroll
    for (int r = 0; r < 4; ++r) sr[r] = __shfl(s_run, 4 * g + r);
#pragma unroll
    for (int tt = 0; tt < 8; ++tt)
#pragma unroll
      for (int r = 0; r < 4; ++r) {
        float v = oacc[tt][r] / sr[r];
        ctx[(size_t)(qw + 4 * g + r) * DM + h * HDIM + tt * 16 + c] = (h16_t)v;
      }
  }
}

// ---------------- merge the 2-chunk partials (qb >= 16) ----------------
__global__ void attn_reduce(const float* __restrict__ Opart, const float* __restrict__ ms,
                            h16_t* __restrict__ ctx) {
  const float L2E = 1.4426950408889634f;
  int b = blockIdx.x;          // 256 = 16 heads x 16 qb
  int h = b & 15, qi = b >> 4; // qb = 16 + qi
  int p0 = (h * 32 + qi * 2);
  int tid = threadIdx.x;
  int row = tid >> 2, seg = (tid & 3) * 32;
  float m1 = ms[p0 * 128 + row], s1 = ms[p0 * 128 + 64 + row];
  float m2 = ms[(p0 + 1) * 128 + row], s2 = ms[(p0 + 1) * 128 + 64 + row];
  float M = fmaxf(m1, m2);
  float w1 = exp2f((m1 - M) * L2E), w2 = exp2f((m2 - M) * L2E);
  float inv = 1.0f / (s1 * w1 + s2 * w2);
  const float* O1 = Opart + (size_t)p0 * 8192 + row * 128 + seg;
  const float* O2 = O1 + 8192;
  h16_t* dst = ctx + (size_t)((16 + qi) * 64 + row) * DM + h * HDIM + seg;
#pragma unroll
  for (int j = 0; j < 32; j += 4) {
    float4 a = *reinterpret_cast<const float4*>(O1 + j);
    float4 c2 = *reinterpret_cast<const float4*>(O2 + j);
    dst[j]     = (h16_t)((a.x * w1 + c2.x * w2) * inv);
    dst[j + 1] = (h16_t)((a.y * w1 + c2.y * w2) * inv);
    dst[j + 2] = (h16_t)((a.z * w1 + c2.z * w2) * inv);
    dst[j + 3] = (h16_t)((a.w * w1 + c2.w * w2) * inv);
  }
}

extern "C" void kernel_launch(void* const* d_in, const int* in_sizes, int n_in,
                              void* d_out, int out_size, void* d_ws, size_t ws_size,
                              hipStream_t stream) {
  const float* hs   = (const float*)d_in[0];
  const float* wqkv = (const float*)d_in[1];
  const float* bqkv = (const float*)d_in[2];
  const float* wo   = (const float*)d_in[3];
  const float* bo   = (const float*)d_in[4];
  float* out = (float*)d_out;

  char* ws = (char*)d_ws;
  const size_t MB = 1u << 20;
  h16_t* h_hi    = (h16_t*)(ws + 0 * MB);    // 8 MB  (reused as ctx16 later)
  h16_t* h_lo    = (h16_t*)(ws + 8 * MB);    // 8 MB
  h16_t* qkvT_hi = (h16_t*)(ws + 16 * MB);   // 24 MB [6144][2048]
  h16_t* woT     = (h16_t*)(ws + 56 * MB);   // 8 MB  [2048][2048]
  h16_t* qk_hi   = (h16_t*)(ws + 64 * MB);   // 16 MB [2048][4096]
  h16_t* qk_lo   = (h16_t*)(ws + 88 * MB);   // 16 MB [2048][4096]
  float2* ctab   = (float2*)(ws + 104 * MB); // 1 MB  [2048][64]
  h16_t* vt      = (h16_t*)(ws + 105 * MB);  // 8 MB  [2048 vc][2048 s]
  // attn partials reuse the qkvT region (consumed before attn):
  float* Opart   = (float*)(ws + 16 * MB);   // 16 MB [512][64][128] fp32
  float* msbuf   = (float*)(ws + 32 * MB);   // 256 KB [512][2][64] fp32
  h16_t* ctx16   = h_hi;

  cvt_split<<<(SEQ * DM / 4 + 255) / 256, 256, 0, stream>>>(hs, h_hi, h_lo, SEQ * DM / 4);
  transpose_f16<<<dim3(QKVW / 64, DM / 64), 256, 0, stream>>>(wqkv, qkvT_hi, DM, QKVW);
  transpose_f16<<<dim3(DM / 64, DM / 64), 256, 0, stream>>>(wo, woT, DM, DM);
  ctab_kernel<<<(SEQ * 64) / 256, 256, 0, stream>>>(ctab);

  // q,k columns: 2-product A-split GEMM + fused RoPE (exact fp32 rotate+resplit)
  gemm_qk<<<dim3(32, 16), 256, 0, stream>>>(
      h_hi, h_lo, qkvT_hi, bqkv, qk_hi, qk_lo, ctab);
  // v columns: Vt[vc][s] = WvT * h^T + bias_v (direct transposed output)
  gemm_v<<<dim3(16, 16), 256, 0, stream>>>(
      qkvT_hi + (size_t)4096 * DM, h_hi, bqkv + 4096, vt);

  attn_kernel<<<768, 256, 0, stream>>>(qk_hi, qk_lo, vt, ctx16, Opart, msbuf);
  attn_reduce<<<256, 256, 0, stream>>>(Opart, msbuf, ctx16);

  gemm_oproj<<<dim3(DM / 128, SEQ / 128), 256, 0, stream>>>(ctx16, woT, bo, out);
}

// Round 12
// 240.070 us; speedup vs baseline: 1.0524x; 1.0524x over previous
//
#include <hip/hip_runtime.h>

typedef _Float16 h16_t;
typedef _Float16 half8 __attribute__((ext_vector_type(8)));
typedef _Float16 half4v __attribute__((ext_vector_type(4)));
typedef float f32x4 __attribute__((ext_vector_type(4)));

#define SEQ 2048
#define DM 2048
#define NHEAD 16
#define HDIM 128
#define QKVW 6144
#define QKW 4096

#define GLOAD_LDS(g, l)                                                   \
  __builtin_amdgcn_global_load_lds(                                       \
      (const __attribute__((address_space(1))) void*)(g),                 \
      (__attribute__((address_space(3))) void*)(l), 16, 0, 0)

#define VMCNT(n) asm volatile("s_waitcnt vmcnt(" #n ")" ::: "memory")

// ---------------- fp32 -> (hi,lo) fp16 split ----------------
__global__ void cvt_split(const float* __restrict__ src, h16_t* __restrict__ hi,
                          h16_t* __restrict__ lo, int n4) {
  int i = blockIdx.x * blockDim.x + threadIdx.x;
  if (i < n4) {
    float4 v = reinterpret_cast<const float4*>(src)[i];
    half4v h, l;
    float x;
    x = v.x; h[0] = (h16_t)x; l[0] = (h16_t)(x - (float)h[0]);
    x = v.y; h[1] = (h16_t)x; l[1] = (h16_t)(x - (float)h[1]);
    x = v.z; h[2] = (h16_t)x; l[2] = (h16_t)(x - (float)h[2]);
    x = v.w; h[3] = (h16_t)x; l[3] = (h16_t)(x - (float)h[3]);
    reinterpret_cast<half4v*>(hi)[i] = h;
    reinterpret_cast<half4v*>(lo)[i] = l;
  }
}

// ------- fp32 W[K][N] -> fp16 Wt[N][K] (hi only), vectorized ----------------
__global__ void transpose_f16(const float* __restrict__ W, h16_t* __restrict__ Wt,
                              int K, int N) {
  __shared__ float tile[64][65];
  int n0 = blockIdx.x * 64, k0 = blockIdx.y * 64;
  int t = threadIdx.x;  // 256
  int row = t >> 4, c4 = t & 15;
#pragma unroll
  for (int j = 0; j < 4; ++j) {
    float4 v = *reinterpret_cast<const float4*>(
        &W[(size_t)(k0 + j * 16 + row) * N + n0 + c4 * 4]);
    tile[j * 16 + row][c4 * 4 + 0] = v.x;
    tile[j * 16 + row][c4 * 4 + 1] = v.y;
    tile[j * 16 + row][c4 * 4 + 2] = v.z;
    tile[j * 16 + row][c4 * 4 + 3] = v.w;
  }
  __syncthreads();
#pragma unroll
  for (int jj = 0; jj < 2; ++jj) {
    int idx = jj * 256 + t;
    int n = idx >> 3, kc = idx & 7;
    half8 hv;
#pragma unroll
    for (int e = 0; e < 8; ++e) hv[e] = (h16_t)tile[kc * 8 + e][n];
    *reinterpret_cast<half8*>(&Wt[(size_t)(n0 + n) * K + k0 + kc * 8]) = hv;
  }
}

// ---------------- cos/sin table [SEQ][64] fp32 ----------------
__global__ void ctab_kernel(float2* __restrict__ tab) {
  int idx = blockIdx.x * blockDim.x + threadIdx.x;  // 2048*64
  int s = idx >> 6, i = idx & 63;
  float freq = 1.0f / powf(10000.0f, (float)(2 * i) / 128.0f);
  float ang = (float)s * freq;
  float sn, cs;
  sincosf(ang, &sn, &cs);
  tab[idx] = make_float2(cs, sn);
}

// ---------------- GEMM body: C[M][N] = A[M][K]*Bt[N][K]^T + bias -----------
// 128x128 tile, BK=32, 4 waves (2x2). R5 schedule (verified):
//   stage(next) | ds_reads | MFMA (setprio) | VMCNT0 | syncthreads.
// ASPLIT: 2-product (Ahi+Alo)*Bhi — removes A-rounding error, keeps W error.
// OUT: 0 = fp16 hi, 1 = fp16 hi+lo, 2 = fp32.
// ROPE: rotate output pairs in-register (tile spans one head) + hi/lo split.
// BROW: bias indexed by output row instead of column.
template <int ASPLIT, int OUT, int ROPE, int BROW>
__device__ __forceinline__ void gemm_body(
    char* smem,
    const h16_t* __restrict__ Ahi, const h16_t* __restrict__ Alo,
    const h16_t* __restrict__ Bhi,
    const float* __restrict__ bias, void* __restrict__ Cout,
    h16_t* __restrict__ Clo, int brow, int bcol, int ldc, int K, int ldlo,
    int tid, const float2* __restrict__ tab) {
  constexpr int BUF = ASPLIT ? 24576 : 16384;
  const int w = tid >> 6, lane = tid & 63, c = lane & 15, g = lane >> 4;
  const int wr = (w >> 1) * 64, wc = (w & 1) * 64;

  f32x4 acc[4][4] = {};

  // stage K-step k0 into buffer bufi (linear dest, inverse-swizzled source)
  auto stage = [&](int bufi, int k0) {
    char* buf = smem + bufi * BUF;
#pragma unroll
    for (int it = 0; it < 2; ++it) {
      int B = it * 256 + tid;
      int row = B >> 2;
      int c8 = (B & 3) ^ ((row >> 1) & 3);
      int loff = it * 4096 + w * 1024;
      GLOAD_LDS(Ahi + (size_t)(brow + row) * K + k0 + c8 * 8, buf + loff);
      GLOAD_LDS(Bhi + (size_t)(bcol + row) * K + k0 + c8 * 8, buf + 8192 + loff);
      if (ASPLIT)
        GLOAD_LDS(Alo + (size_t)(brow + row) * K + k0 + c8 * 8, buf + 16384 + loff);
    }
  };

  int cur = 0;
  stage(0, 0);
  VMCNT(0);
  __syncthreads();

#pragma unroll 1
  for (int k0 = 0; k0 < K; k0 += 32) {
    if (k0 + 32 < K) stage(cur ^ 1, k0 + 32);
    const char* bufc = smem + cur * BUF;
    half8 afh[4], bfh[4], afl[4];
#pragma unroll
    for (int f = 0; f < 4; ++f) {
      int rowa = wr + f * 16 + c;
      int offa = rowa * 64 + ((g ^ ((rowa >> 1) & 3)) * 16);
      int rowb = wc + f * 16 + c;
      int offb = rowb * 64 + ((g ^ ((rowb >> 1) & 3)) * 16);
      afh[f] = *reinterpret_cast<const half8*>(bufc + offa);
      bfh[f] = *reinterpret_cast<const half8*>(bufc + 8192 + offb);
      if (ASPLIT) afl[f] = *reinterpret_cast<const half8*>(bufc + 16384 + offa);
    }
    __builtin_amdgcn_s_setprio(1);
#pragma unroll
    for (int fm = 0; fm < 4; ++fm)
#pragma unroll
      for (int fn = 0; fn < 4; ++fn) {
        acc[fm][fn] = __builtin_amdgcn_mfma_f32_16x16x32_f16(afh[fm], bfh[fn], acc[fm][fn], 0, 0, 0);
        if (ASPLIT)
          acc[fm][fn] = __builtin_amdgcn_mfma_f32_16x16x32_f16(afl[fm], bfh[fn], acc[fm][fn], 0, 0, 0);
      }
    __builtin_amdgcn_s_setprio(0);
    VMCNT(0);
    __syncthreads();
    cur ^= 1;
  }

  const float fac = (ROPE && bcol < 2048) ? 11.31370849898476f : 1.0f;
#pragma unroll
  for (int fm = 0; fm < 4; ++fm)
#pragma unroll
    for (int fn = 0; fn < 4; ++fn) {
      int col = bcol + wc + fn * 16 + c;
      float bv = BROW ? 0.f : bias[col];
#pragma unroll
      for (int r = 0; r < 4; ++r) {
        int row = brow + wr + fm * 16 + 4 * g + r;
        float v = acc[fm][fn][r] + (BROW ? bias[row] : bv);
        if (ROPE) {
          // pair (2i,2i+1) sits on adjacent lanes (c even/odd)
          float pv = __shfl_xor(v, 1);
          float2 cc = tab[row * 64 + ((col & 127) >> 1)];
          float y = (col & 1) ? (v * cc.x + pv * cc.y) * fac
                              : (v * cc.x - pv * cc.y) * fac;
          h16_t hv = (h16_t)y;
          ((h16_t*)Cout)[(size_t)row * ldc + col] = hv;
          Clo[(size_t)row * ldlo + col] = (h16_t)(y - (float)hv);
        } else if (OUT == 2) {
          ((float*)Cout)[(size_t)row * ldc + col] = v;
        } else {
          h16_t hv = (h16_t)v;
          ((h16_t*)Cout)[(size_t)row * ldc + col] = hv;
          if (OUT == 1) Clo[(size_t)row * ldlo + col] = (h16_t)(v - (float)hv);
        }
      }
    }
}

// ---------------- q,k columns: 2-product A-split GEMM + fused RoPE ----------
__global__ __launch_bounds__(256) void gemm_qk(
    const h16_t* __restrict__ h_hi, const h16_t* __restrict__ h_lo,
    const h16_t* __restrict__ qkvT_hi, const float* __restrict__ bqkv,
    h16_t* __restrict__ qk_hi, h16_t* __restrict__ qk_lo,
    const float2* __restrict__ tab) {
  __shared__ __align__(16) char smem[49152];
  gemm_body<1, 1, 1, 0>(smem, h_hi, h_lo, qkvT_hi, bqkv, qk_hi, qk_lo,
                        blockIdx.y * 128, blockIdx.x * 128, QKW, DM, QKW,
                        threadIdx.x, tab);
}

// ---------------- v columns -> Vt[vc][s] directly (operands swapped) --------
__global__ __launch_bounds__(256) void gemm_v(
    const h16_t* __restrict__ wvT_hi, const h16_t* __restrict__ h_hi,
    const float* __restrict__ bias_v, h16_t* __restrict__ vt) {
  __shared__ __align__(16) char smem[32768];
  gemm_body<0, 0, 0, 1>(smem, wvT_hi, nullptr, h_hi, bias_v, vt,
                        nullptr, blockIdx.y * 128, blockIdx.x * 128, SEQ, DM, 0,
                        threadIdx.x, nullptr);
}

// ---------------- out-projection GEMM (fp32 out) ----------------
__global__ __launch_bounds__(256) void gemm_oproj(
    const h16_t* __restrict__ A, const h16_t* __restrict__ Bt,
    const float* __restrict__ bias, float* __restrict__ Cout) {
  __shared__ __align__(16) char smem[32768];
  gemm_body<0, 2, 0, 0>(smem, A, nullptr, Bt, bias, Cout, nullptr,
                        blockIdx.y * 128, blockIdx.x * 128, DM, DM, 0,
                        threadIdx.x, nullptr);
}

// ---------------- causal flash attention, split-K, balanced 3-slot ----------
// 768 blocks, all co-resident (3/CU). h = p&15 (XCD-pinned), cq = p>>4.
// Under breadth-first dispatch, CU(p) == CU(p+256) == CU(p+512), so per-CU
// work = nt(slot1) + nt(slot2) + nt(slot3). Slot orders chosen so the sum is
// UNIFORM (= 66 tiles):
//   cq<16 : qb=16+cq, keys [0,1024)         -> chunk 0, nt=32       (slot 1)
//   cq<32 : qb=47-cq, keys [1024,..)        -> chunk 1, nt=32-2s    (slot 2)
//   else  : qb=cq-32 (ASCENDING), all keys  -> direct,  nt=2+2s     (slot 3)
// 2-buffer pipeline (48KB LDS -> 3 blocks/CU), R5 order: vmcnt(0) | barrier |
// stage(i+1) | compute. Per-lane deferred denominator; hoisted causal mask.
__global__ __launch_bounds__(256) void attn_kernel(const h16_t* __restrict__ qhi,
                                                   const h16_t* __restrict__ qlo,
                                                   const h16_t* __restrict__ vt,
                                                   h16_t* __restrict__ ctx,
                                                   float* __restrict__ Opart,
                                                   float* __restrict__ ms) {
  __shared__ __align__(16) char smem[2 * 24576];
  const int tid = threadIdx.x, w = tid >> 6, lane = tid & 63, c = lane & 15, g = lane >> 4;
  const int p = blockIdx.x;
  const int h = p & 15;
  const int cq = p >> 4;
  int qb, t0, nt, pidx;
  if (cq < 16)      { qb = 16 + cq; t0 = 0;  nt = 32;          pidx = h * 32 + cq * 2; }
  else if (cq < 32) { qb = 47 - cq; t0 = 32; nt = 2 * qb - 30; pidx = h * 32 + (qb - 16) * 2 + 1; }
  else              { qb = cq - 32; t0 = 0;  nt = 2 * qb + 2;  pidx = -1; }

  const h16_t* Kph = qhi + 2048 + h * HDIM;
  const h16_t* Kpl = qlo + 2048 + h * HDIM;
  const h16_t* Vth = vt + (size_t)h * HDIM * SEQ;
  const float L2E = 1.4426950408889634f;

  const int q0 = qb * 64;
  const int qw = q0 + w * 16;

  // stage one KVBLK=32 tile (Khi, Klo row-major swizzled; Vt [128 d][32 key])
  auto stage = [&](int bufi, int t) {
    char* buf = smem + bufi * 24576;
    const int k0 = t * 32;
#pragma unroll
    for (int it = 0; it < 2; ++it) {
      int B = it * 256 + tid;
      int loff = it * 4096 + w * 1024;
      int row = B >> 4;                       // key row 0..31
      int c16 = (B & 15) ^ (row & 7);
      GLOAD_LDS(Kph + (size_t)(k0 + row) * QKW + c16 * 8, buf + loff);
      GLOAD_LDS(Kpl + (size_t)(k0 + row) * QKW + c16 * 8, buf + 8192 + loff);
      int rv = B >> 2;                        // d row 0..127
      int c4 = (B & 3) ^ ((rv >> 1) & 3);
      GLOAD_LDS(Vth + (size_t)rv * SEQ + k0 + c4 * 8, buf + 16384 + loff);
    }
  };

  half8 qfh[4], qfl[4];
#pragma unroll
  for (int kc = 0; kc < 4; ++kc) {
    qfh[kc] = *reinterpret_cast<const half8*>(qhi + (size_t)(qw + c) * QKW + h * HDIM + kc * 32 + g * 8);
    qfl[kc] = *reinterpret_cast<const half8*>(qlo + (size_t)(qw + c) * QKW + h * HDIM + kc * 32 + g * 8);
  }

  f32x4 oacc[8] = {};
  float m_run = -3.0e38f, s_part = 0.f;

  stage(0, t0);

#pragma unroll 1
  for (int i = 0; i < nt; ++i) {
    // stage(i) was issued one full compute-phase ago; nothing else in flight.
    VMCNT(0);
    __builtin_amdgcn_s_barrier();
    __builtin_amdgcn_sched_barrier(0);
    if (i + 1 < nt) stage((i + 1) & 1, t0 + i + 1);
    __builtin_amdgcn_sched_barrier(0);

    const int k0 = (t0 + i) * 32;
    const char* buf = smem + (i & 1) * 24576;
    const char* bufV = buf + 16384;

    // S^T = K * Q, 3-product split (32 keys x 16 q per wave)
    f32x4 st[2] = {};
    __builtin_amdgcn_s_setprio(1);
#pragma unroll
    for (int kc = 0; kc < 4; ++kc)
#pragma unroll
      for (int fm = 0; fm < 2; ++fm) {
        int row = fm * 16 + c;
        int so = row * 256 + (((4 * kc + g) ^ (row & 7)) * 16);
        half8 kfh = *reinterpret_cast<const half8*>(buf + so);
        half8 kfl = *reinterpret_cast<const half8*>(buf + 8192 + so);
        st[fm] = __builtin_amdgcn_mfma_f32_16x16x32_f16(kfh, qfh[kc], st[fm], 0, 0, 0);
        st[fm] = __builtin_amdgcn_mfma_f32_16x16x32_f16(kfh, qfl[kc], st[fm], 0, 0, 0);
        st[fm] = __builtin_amdgcn_mfma_f32_16x16x32_f16(kfl, qfh[kc], st[fm], 0, 0, 0);
      }
    __builtin_amdgcn_s_setprio(0);

    // causal mask (hoisted, wave-uniform) + online softmax (defer-max THR=8,
    // per-lane deferred denominator; scale pre-folded into q)
    float p_[2][4];
    float tmax = -3.0e38f;
    const int qg = qw + c;
    const bool needmask = (k0 + 31 > qw);
#pragma unroll
    for (int fm = 0; fm < 2; ++fm)
#pragma unroll
      for (int r = 0; r < 4; ++r) {
        float sf = st[fm][r];
        if (needmask) {
          int key = k0 + fm * 16 + 4 * g + r;
          sf = (key > qg) ? -3.0e38f : sf;
        }
        p_[fm][r] = sf;
        tmax = fmaxf(tmax, sf);
      }
    tmax = fmaxf(tmax, __shfl_xor(tmax, 16));
    tmax = fmaxf(tmax, __shfl_xor(tmax, 32));
    if (!__all(tmax - m_run <= 8.0f)) {
      float m_new = fmaxf(m_run, tmax);
      float alpha = exp2f((m_run - m_new) * L2E);
      float ar[4];
#pragma unroll
      for (int r = 0; r < 4; ++r) ar[r] = __shfl(alpha, 4 * g + r);
#pragma unroll
      for (int tt = 0; tt < 8; ++tt)
#pragma unroll
        for (int r = 0; r < 4; ++r) oacc[tt][r] *= ar[r];
      s_part *= alpha;
      m_run = m_new;
    }
#pragma unroll
    for (int fm = 0; fm < 2; ++fm)
#pragma unroll
      for (int r = 0; r < 4; ++r) {
        float e = exp2f((p_[fm][r] - m_run) * L2E);
        p_[fm][r] = e;
        s_part += e;
      }

    // pack P fragment: slot i <-> key 16*(i>>2) + 4g + (i&3)  (per-lane, free)
    half8 ap;
#pragma unroll
    for (int j = 0; j < 8; ++j) ap[j] = (h16_t)p_[j >> 2][j & 3];

    // PV: B-frag = two swizzled b64 reads of Vt (keys 4g..4g+3, 16+4g..16+4g+3)
    __builtin_amdgcn_s_setprio(1);
#pragma unroll
    for (int tt = 0; tt < 8; ++tt) {
      int row = 16 * tt + c;
      int sw = (row >> 1) & 3;
      int b1 = (g >> 1), b2 = 2 + (g >> 1);
      int a1 = row * 64 + (((b1 ^ sw)) * 16) + 8 * (g & 1);
      int a2 = row * 64 + (((b2 ^ sw)) * 16) + 8 * (g & 1);
      union { half8 v8; half4v v4[2]; } u;
      u.v4[0] = *reinterpret_cast<const half4v*>(bufV + a1);
      u.v4[1] = *reinterpret_cast<const half4v*>(bufV + a2);
      oacc[tt] = __builtin_amdgcn_mfma_f32_16x16x32_f16(ap, u.v8, oacc[tt], 0, 0, 0);
    }
    __builtin_amdgcn_s_setprio(0);
  }

  // final cross-lane denominator reduce (deferred from the loop)
  float s_run = s_part;
  s_run += __shfl_xor(s_run, 16);
  s_run += __shfl_xor(s_run, 32);

  if (pidx >= 0) {
    // partial: store fp32 O, m, s (consistent w.r.t. m_run reference point)
    float* Od = Opart + (size_t)pidx * 8192;
#pragma unroll
    for (int tt = 0; tt < 8; ++tt)
#pragma unroll
      for (int r = 0; r < 4; ++r)
        Od[(w * 16 + 4 * g + r) * 128 + tt * 16 + c] = oacc[tt][r];
    if (lane < 16) {
      ms[pidx * 128 + w * 16 + c] = m_run;
      ms[pidx * 128 + 64 + w * 16 + c] = s_run;
    }
  } else {
    float sr[4];
#pragma unroll
    for (int r = 0; r < 4; ++r) sr[r] = __shfl(s_run, 4 * g + r);
#pragma unroll
    for (int tt = 0; tt < 8; ++tt)
#pragma unroll
      for (int r = 0; r < 4; ++r) {
        float v = oacc[tt][r] / sr[r];
        ctx[(size_t)(qw + 4 * g + r) * DM + h * HDIM + tt * 16 + c] = (h16_t)v;
      }
  }
}

// ---------------- merge the 2-chunk partials (qb >= 16) ----------------
__global__ void attn_reduce(const float* __restrict__ Opart, const float* __restrict__ ms,
                            h16_t* __restrict__ ctx) {
  const float L2E = 1.4426950408889634f;
  int b = blockIdx.x;          // 256 = 16 heads x 16 qb
  int h = b & 15, qi = b >> 4; // qb = 16 + qi
  int p0 = (h * 32 + qi * 2);
  int tid = threadIdx.x;
  int row = tid >> 2, seg = (tid & 3) * 32;
  float m1 = ms[p0 * 128 + row], s1 = ms[p0 * 128 + 64 + row];
  float m2 = ms[(p0 + 1) * 128 + row], s2 = ms[(p0 + 1) * 128 + 64 + row];
  float M = fmaxf(m1, m2);
  float w1 = exp2f((m1 - M) * L2E), w2 = exp2f((m2 - M) * L2E);
  float inv = 1.0f / (s1 * w1 + s2 * w2);
  const float* O1 = Opart + (size_t)p0 * 8192 + row * 128 + seg;
  const float* O2 = O1 + 8192;
  h16_t* dst = ctx + (size_t)((16 + qi) * 64 + row) * DM + h * HDIM + seg;
#pragma unroll
  for (int j = 0; j < 32; j += 4) {
    float4 a = *reinterpret_cast<const float4*>(O1 + j);
    float4 c2 = *reinterpret_cast<const float4*>(O2 + j);
    dst[j]     = (h16_t)((a.x * w1 + c2.x * w2) * inv);
    dst[j + 1] = (h16_t)((a.y * w1 + c2.y * w2) * inv);
    dst[j + 2] = (h16_t)((a.z * w1 + c2.z * w2) * inv);
    dst[j + 3] = (h16_t)((a.w * w1 + c2.w * w2) * inv);
  }
}

extern "C" void kernel_launch(void* const* d_in, const int* in_sizes, int n_in,
                              void* d_out, int out_size, void* d_ws, size_t ws_size,
                              hipStream_t stream) {
  const float* hs   = (const float*)d_in[0];
  const float* wqkv = (const float*)d_in[1];
  const float* bqkv = (const float*)d_in[2];
  const float* wo   = (const float*)d_in[3];
  const float* bo   = (const float*)d_in[4];
  float* out = (float*)d_out;

  char* ws = (char*)d_ws;
  const size_t MB = 1u << 20;
  h16_t* h_hi    = (h16_t*)(ws + 0 * MB);    // 8 MB  (reused as ctx16 later)
  h16_t* h_lo    = (h16_t*)(ws + 8 * MB);    // 8 MB
  h16_t* qkvT_hi = (h16_t*)(ws + 16 * MB);   // 24 MB [6144][2048]
  h16_t* woT     = (h16_t*)(ws + 56 * MB);   // 8 MB  [2048][2048]
  h16_t* qk_hi   = (h16_t*)(ws + 64 * MB);   // 16 MB [2048][4096]
  h16_t* qk_lo   = (h16_t*)(ws + 88 * MB);   // 16 MB [2048][4096]
  float2* ctab   = (float2*)(ws + 104 * MB); // 1 MB  [2048][64]
  h16_t* vt      = (h16_t*)(ws + 105 * MB);  // 8 MB  [2048 vc][2048 s]
  // attn partials reuse the qkvT region (consumed before attn):
  float* Opart   = (float*)(ws + 16 * MB);   // 16 MB [512][64][128] fp32
  float* msbuf   = (float*)(ws + 32 * MB);   // 256 KB [512][2][64] fp32
  h16_t* ctx16   = h_hi;

  cvt_split<<<(SEQ * DM / 4 + 255) / 256, 256, 0, stream>>>(hs, h_hi, h_lo, SEQ * DM / 4);
  transpose_f16<<<dim3(QKVW / 64, DM / 64), 256, 0, stream>>>(wqkv, qkvT_hi, DM, QKVW);
  transpose_f16<<<dim3(DM / 64, DM / 64), 256, 0, stream>>>(wo, woT, DM, DM);
  ctab_kernel<<<(SEQ * 64) / 256, 256, 0, stream>>>(ctab);

  // q,k columns: 2-product A-split GEMM + fused RoPE (exact fp32 rotate+resplit)
  gemm_qk<<<dim3(32, 16), 256, 0, stream>>>(
      h_hi, h_lo, qkvT_hi, bqkv, qk_hi, qk_lo, ctab);
  // v columns: Vt[vc][s] = WvT * h^T + bias_v (direct transposed output)
  gemm_v<<<dim3(16, 16), 256, 0, stream>>>(
      qkvT_hi + (size_t)4096 * DM, h_hi, bqkv + 4096, vt);

  attn_kernel<<<768, 256, 0, stream>>>(qk_hi, qk_lo, vt, ctx16, Opart, msbuf);
  attn_reduce<<<256, 256, 0, stream>>>(Opart, msbuf, ctx16);

  gemm_oproj<<<dim3(DM / 128, SEQ / 128), 256, 0, stream>>>(ctx16, woT, bo, out);
}

// Round 14
// 236.628 us; speedup vs baseline: 1.0677x; 1.0145x over previous
//
#include <hip/hip_runtime.h>

typedef _Float16 h16_t;
typedef _Float16 half8 __attribute__((ext_vector_type(8)));
typedef _Float16 half4v __attribute__((ext_vector_type(4)));
typedef float f32x4 __attribute__((ext_vector_type(4)));

#define SEQ 2048
#define DM 2048
#define NHEAD 16
#define HDIM 128
#define QKVW 6144
#define QKW 4096

#define GLOAD_LDS(g, l)                                                   \
  __builtin_amdgcn_global_load_lds(                                       \
      (const __attribute__((address_space(1))) void*)(g),                 \
      (__attribute__((address_space(3))) void*)(l), 16, 0, 0)

#define VMCNT(n) asm volatile("s_waitcnt vmcnt(" #n ")" ::: "memory")

// ------- fused small prep: fp32->(hi,lo) split (p<4096) + cos/sin table -----
__global__ void prep_small(const float* __restrict__ src, h16_t* __restrict__ hi,
                           h16_t* __restrict__ lo, float2* __restrict__ tab) {
  int p = blockIdx.x;
  if (p < 4096) {
    int i = p * 256 + threadIdx.x;  // SEQ*DM/4 = 1048576 float4s
    float4 v = reinterpret_cast<const float4*>(src)[i];
    half4v h, l;
    float x;
    x = v.x; h[0] = (h16_t)x; l[0] = (h16_t)(x - (float)h[0]);
    x = v.y; h[1] = (h16_t)x; l[1] = (h16_t)(x - (float)h[1]);
    x = v.z; h[2] = (h16_t)x; l[2] = (h16_t)(x - (float)h[2]);
    x = v.w; h[3] = (h16_t)x; l[3] = (h16_t)(x - (float)h[3]);
    reinterpret_cast<half4v*>(hi)[i] = h;
    reinterpret_cast<half4v*>(lo)[i] = l;
  } else {
    int idx = (p - 4096) * 256 + threadIdx.x;  // 2048*64
    int s = idx >> 6, i = idx & 63;
    float freq = 1.0f / powf(10000.0f, (float)(2 * i) / 128.0f);
    float ang = (float)s * freq;
    float sn, cs;
    sincosf(ang, &sn, &cs);
    tab[idx] = make_float2(cs, sn);
  }
}

// ------- fused weight transposes: wqkv (p<3072) + wo, fp32->fp16 Wt[N][K] ---
__global__ void transpose_both(const float* __restrict__ Wqkv,
                               const float* __restrict__ Wo,
                               h16_t* __restrict__ qkvT, h16_t* __restrict__ woT) {
  __shared__ float tile[64][65];
  int p = blockIdx.x;
  const float* W;
  h16_t* Wt;
  int N, bx, by;
  if (p < 3072) { W = Wqkv; Wt = qkvT; N = QKVW; bx = p % 96; by = p / 96; }
  else          { int q = p - 3072; W = Wo; Wt = woT; N = DM; bx = q % 32; by = q / 32; }
  int n0 = bx * 64, k0 = by * 64;
  int t = threadIdx.x;  // 256
  int row = t >> 4, c4 = t & 15;
#pragma unroll
  for (int j = 0; j < 4; ++j) {
    float4 v = *reinterpret_cast<const float4*>(
        &W[(size_t)(k0 + j * 16 + row) * N + n0 + c4 * 4]);
    tile[j * 16 + row][c4 * 4 + 0] = v.x;
    tile[j * 16 + row][c4 * 4 + 1] = v.y;
    tile[j * 16 + row][c4 * 4 + 2] = v.z;
    tile[j * 16 + row][c4 * 4 + 3] = v.w;
  }
  __syncthreads();
#pragma unroll
  for (int jj = 0; jj < 2; ++jj) {
    int idx = jj * 256 + t;
    int n = idx >> 3, kc = idx & 7;
    half8 hv;
#pragma unroll
    for (int e = 0; e < 8; ++e) hv[e] = (h16_t)tile[kc * 8 + e][n];
    *reinterpret_cast<half8*>(&Wt[(size_t)(n0 + n) * DM + k0 + kc * 8]) = hv;
  }
}

// ---------------- GEMM body: C[M][N] = A[M][K]*Bt[N][K]^T + bias -----------
// 128x128 tile, BK=32, 4 waves (2x2). R5 schedule (verified):
//   stage(next) | ds_reads | MFMA (setprio) | VMCNT0 | syncthreads.
// ASPLIT: 2-product (Ahi+Alo)*Bhi — removes A-rounding error, keeps W error.
// OUT: 0 = fp16 hi, 2 = fp32.  ROPE: rotate output pairs in-register (tile
// spans one head) + hi/lo re-split.  BROW: bias indexed by output row.
template <int ASPLIT, int OUT, int ROPE, int BROW>
__device__ __forceinline__ void gemm_body(
    char* smem,
    const h16_t* __restrict__ Ahi, const h16_t* __restrict__ Alo,
    const h16_t* __restrict__ Bhi,
    const float* __restrict__ bias, void* __restrict__ Cout,
    h16_t* __restrict__ Clo, int brow, int bcol, int ldc, int K, int ldlo,
    int tid, const float2* __restrict__ tab) {
  constexpr int BUF = ASPLIT ? 24576 : 16384;
  const int w = tid >> 6, lane = tid & 63, c = lane & 15, g = lane >> 4;
  const int wr = (w >> 1) * 64, wc = (w & 1) * 64;

  f32x4 acc[4][4] = {};

  // stage K-step k0 into buffer bufi (linear dest, inverse-swizzled source)
  auto stage = [&](int bufi, int k0) {
    char* buf = smem + bufi * BUF;
#pragma unroll
    for (int it = 0; it < 2; ++it) {
      int B = it * 256 + tid;
      int row = B >> 2;
      int c8 = (B & 3) ^ ((row >> 1) & 3);
      int loff = it * 4096 + w * 1024;
      GLOAD_LDS(Ahi + (size_t)(brow + row) * K + k0 + c8 * 8, buf + loff);
      GLOAD_LDS(Bhi + (size_t)(bcol + row) * K + k0 + c8 * 8, buf + 8192 + loff);
      if (ASPLIT)
        GLOAD_LDS(Alo + (size_t)(brow + row) * K + k0 + c8 * 8, buf + 16384 + loff);
    }
  };

  int cur = 0;
  stage(0, 0);
  VMCNT(0);
  __syncthreads();

#pragma unroll 1
  for (int k0 = 0; k0 < K; k0 += 32) {
    if (k0 + 32 < K) stage(cur ^ 1, k0 + 32);
    const char* bufc = smem + cur * BUF;
    half8 afh[4], bfh[4], afl[4];
#pragma unroll
    for (int f = 0; f < 4; ++f) {
      int rowa = wr + f * 16 + c;
      int offa = rowa * 64 + ((g ^ ((rowa >> 1) & 3)) * 16);
      int rowb = wc + f * 16 + c;
      int offb = rowb * 64 + ((g ^ ((rowb >> 1) & 3)) * 16);
      afh[f] = *reinterpret_cast<const half8*>(bufc + offa);
      bfh[f] = *reinterpret_cast<const half8*>(bufc + 8192 + offb);
      if (ASPLIT) afl[f] = *reinterpret_cast<const half8*>(bufc + 16384 + offa);
    }
    __builtin_amdgcn_s_setprio(1);
#pragma unroll
    for (int fm = 0; fm < 4; ++fm)
#pragma unroll
      for (int fn = 0; fn < 4; ++fn) {
        acc[fm][fn] = __builtin_amdgcn_mfma_f32_16x16x32_f16(afh[fm], bfh[fn], acc[fm][fn], 0, 0, 0);
        if (ASPLIT)
          acc[fm][fn] = __builtin_amdgcn_mfma_f32_16x16x32_f16(afl[fm], bfh[fn], acc[fm][fn], 0, 0, 0);
      }
    __builtin_amdgcn_s_setprio(0);
    VMCNT(0);
    __syncthreads();
    cur ^= 1;
  }

  const float fac = (ROPE && bcol < 2048) ? 11.31370849898476f : 1.0f;
#pragma unroll
  for (int fm = 0; fm < 4; ++fm)
#pragma unroll
    for (int fn = 0; fn < 4; ++fn) {
      int col = bcol + wc + fn * 16 + c;
      float bv = BROW ? 0.f : bias[col];
#pragma unroll
      for (int r = 0; r < 4; ++r) {
        int row = brow + wr + fm * 16 + 4 * g + r;
        float v = acc[fm][fn][r] + (BROW ? bias[row] : bv);
        if (ROPE) {
          // pair (2i,2i+1) sits on adjacent lanes (c even/odd)
          float pv = __shfl_xor(v, 1);
          float2 cc = tab[row * 64 + ((col & 127) >> 1)];
          float y = (col & 1) ? (v * cc.x + pv * cc.y) * fac
                              : (v * cc.x - pv * cc.y) * fac;
          h16_t hv = (h16_t)y;
          ((h16_t*)Cout)[(size_t)row * ldc + col] = hv;
          Clo[(size_t)row * ldlo + col] = (h16_t)(y - (float)hv);
        } else if (OUT == 2) {
          ((float*)Cout)[(size_t)row * ldc + col] = v;
        } else {
          ((h16_t*)Cout)[(size_t)row * ldc + col] = (h16_t)v;
        }
      }
    }
}

// ---------------- q,k columns: 2-product A-split GEMM + fused RoPE ----------
__global__ __launch_bounds__(256) void gemm_qk(
    const h16_t* __restrict__ h_hi, const h16_t* __restrict__ h_lo,
    const h16_t* __restrict__ qkvT_hi, const float* __restrict__ bqkv,
    h16_t* __restrict__ qk_hi, h16_t* __restrict__ qk_lo,
    const float2* __restrict__ tab) {
  __shared__ __align__(16) char smem[49152];
  gemm_body<1, 0, 1, 0>(smem, h_hi, h_lo, qkvT_hi, bqkv, qk_hi, qk_lo,
                        blockIdx.y * 128, blockIdx.x * 128, QKW, DM, QKW,
                        threadIdx.x, tab);
}

// ---------------- v columns -> Vt[vc][s] directly (operands swapped) --------
__global__ __launch_bounds__(256) void gemm_v(
    const h16_t* __restrict__ wvT_hi, const h16_t* __restrict__ h_hi,
    const float* __restrict__ bias_v, h16_t* __restrict__ vt) {
  __shared__ __align__(16) char smem[32768];
  gemm_body<0, 0, 0, 1>(smem, wvT_hi, nullptr, h_hi, bias_v, vt, nullptr,
                        blockIdx.y * 128, blockIdx.x * 128, SEQ, DM, 0,
                        threadIdx.x, nullptr);
}

// ---------------- out-projection GEMM (fp32 out) ----------------
__global__ __launch_bounds__(256) void gemm_oproj(
    const h16_t* __restrict__ A, const h16_t* __restrict__ Bt,
    const float* __restrict__ bias, float* __restrict__ Cout) {
  __shared__ __align__(16) char smem[32768];
  gemm_body<0, 2, 0, 0>(smem, A, nullptr, Bt, bias, Cout, nullptr,
                        blockIdx.y * 128, blockIdx.x * 128, DM, DM, 0,
                        threadIdx.x, nullptr);
}

// ---------------- causal flash attention, split-K, balanced 3-slot ----------
// 768 blocks, all co-resident (3/CU). h = p&15 (XCD-pinned), cq = p>>4.
// Per-CU work = nt(slot1)+nt(slot2)+nt(slot3) = 66 tiles uniform:
//   cq<16 : qb=16+cq, keys [0,1024)         -> chunk 0, nt=32       (slot 1)
//   cq<32 : qb=47-cq, keys [1024,..)        -> chunk 1, nt=32-2s    (slot 2)
//   else  : qb=cq-32 (ASCENDING), all keys  -> direct,  nt=2+2s     (slot 3)
// 2-buffer pipeline (48KB LDS -> 3 blocks/CU), R5 order: vmcnt(0) | barrier |
// stage(i+1) | compute. Per-lane deferred denominator; hoisted causal mask.
__global__ __launch_bounds__(256) void attn_kernel(const h16_t* __restrict__ qhi,
                                                   const h16_t* __restrict__ qlo,
                                                   const h16_t* __restrict__ vt,
                                                   h16_t* __restrict__ ctx,
                                                   float* __restrict__ Opart,
                                                   float* __restrict__ ms) {
  __shared__ __align__(16) char smem[2 * 24576];
  const int tid = threadIdx.x, w = tid >> 6, lane = tid & 63, c = lane & 15, g = lane >> 4;
  const int p = blockIdx.x;
  const int h = p & 15;
  const int cq = p >> 4;
  int qb, t0, nt, pidx;
  if (cq < 16)      { qb = 16 + cq; t0 = 0;  nt = 32;          pidx = h * 32 + cq * 2; }
  else if (cq < 32) { qb = 47 - cq; t0 = 32; nt = 2 * qb - 30; pidx = h * 32 + (qb - 16) * 2 + 1; }
  else              { qb = cq - 32; t0 = 0;  nt = 2 * qb + 2;  pidx = -1; }

  const h16_t* Kph = qhi + 2048 + h * HDIM;
  const h16_t* Kpl = qlo + 2048 + h * HDIM;
  const h16_t* Vth = vt + (size_t)h * HDIM * SEQ;
  const float L2E = 1.4426950408889634f;

  const int q0 = qb * 64;
  const int qw = q0 + w * 16;

  // stage one KVBLK=32 tile (Khi, Klo row-major swizzled; Vt [128 d][32 key])
  auto stage = [&](int bufi, int t) {
    char* buf = smem + bufi * 24576;
    const int k0 = t * 32;
#pragma unroll
    for (int it = 0; it < 2; ++it) {
      int B = it * 256 + tid;
      int loff = it * 4096 + w * 1024;
      int row = B >> 4;                       // key row 0..31
      int c16 = (B & 15) ^ (row & 7);
      GLOAD_LDS(Kph + (size_t)(k0 + row) * QKW + c16 * 8, buf + loff);
      GLOAD_LDS(Kpl + (size_t)(k0 + row) * QKW + c16 * 8, buf + 8192 + loff);
      int rv = B >> 2;                        // d row 0..127
      int c4 = (B & 3) ^ ((rv >> 1) & 3);
      GLOAD_LDS(Vth + (size_t)rv * SEQ + k0 + c4 * 8, buf + 16384 + loff);
    }
  };

  half8 qfh[4], qfl[4];
#pragma unroll
  for (int kc = 0; kc < 4; ++kc) {
    qfh[kc] = *reinterpret_cast<const half8*>(qhi + (size_t)(qw + c) * QKW + h * HDIM + kc * 32 + g * 8);
    qfl[kc] = *reinterpret_cast<const half8*>(qlo + (size_t)(qw + c) * QKW + h * HDIM + kc * 32 + g * 8);
  }

  f32x4 oacc[8] = {};
  float m_run = -3.0e38f, s_part = 0.f;

  stage(0, t0);

#pragma unroll 1
  for (int i = 0; i < nt; ++i) {
    // stage(i) was issued one full compute-phase ago; nothing else in flight.
    VMCNT(0);
    __builtin_amdgcn_s_barrier();
    __builtin_amdgcn_sched_barrier(0);
    if (i + 1 < nt) stage((i + 1) & 1, t0 + i + 1);
    __builtin_amdgcn_sched_barrier(0);

    const int k0 = (t0 + i) * 32;
    const char* buf = smem + (i & 1) * 24576;
    const char* bufV = buf + 16384;

    // S^T = K * Q, 3-product split (32 keys x 16 q per wave)
    f32x4 st[2] = {};
    __builtin_amdgcn_s_setprio(1);
#pragma unroll
    for (int kc = 0; kc < 4; ++kc)
#pragma unroll
      for (int fm = 0; fm < 2; ++fm) {
        int row = fm * 16 + c;
        int so = row * 256 + (((4 * kc + g) ^ (row & 7)) * 16);
        half8 kfh = *reinterpret_cast<const half8*>(buf + so);
        half8 kfl = *reinterpret_cast<const half8*>(buf + 8192 + so);
        st[fm] = __builtin_amdgcn_mfma_f32_16x16x32_f16(kfh, qfh[kc], st[fm], 0, 0, 0);
        st[fm] = __builtin_amdgcn_mfma_f32_16x16x32_f16(kfh, qfl[kc], st[fm], 0, 0, 0);
        st[fm] = __builtin_amdgcn_mfma_f32_16x16x32_f16(kfl, qfh[kc], st[fm], 0, 0, 0);
      }
    __builtin_amdgcn_s_setprio(0);

    // causal mask (hoisted, wave-uniform) + online softmax (defer-max THR=8,
    // per-lane deferred denominator; scale pre-folded into q)
    float p_[2][4];
    float tmax = -3.0e38f;
    const int qg = qw + c;
    const bool needmask = (k0 + 31 > qw);
#pragma unroll
    for (int fm = 0; fm < 2; ++fm)
#pragma unroll
      for (int r = 0; r < 4; ++r) {
        float sf = st[fm][r];
        if (needmask) {
          int key = k0 + fm * 16 + 4 * g + r;
          sf = (key > qg) ? -3.0e38f : sf;
        }
        p_[fm][r] = sf;
        tmax = fmaxf(tmax, sf);
      }
    tmax = fmaxf(tmax, __shfl_xor(tmax, 16));
    tmax = fmaxf(tmax, __shfl_xor(tmax, 32));
    if (!__all(tmax - m_run <= 8.0f)) {
      float m_new = fmaxf(m_run, tmax);
      float alpha = exp2f((m_run - m_new) * L2E);
      float ar[4];
#pragma unroll
      for (int r = 0; r < 4; ++r) ar[r] = __shfl(alpha, 4 * g + r);
#pragma unroll
      for (int tt = 0; tt < 8; ++tt)
#pragma unroll
        for (int r = 0; r < 4; ++r) oacc[tt][r] *= ar[r];
      s_part *= alpha;
      m_run = m_new;
    }
#pragma unroll
    for (int fm = 0; fm < 2; ++fm)
#pragma unroll
      for (int r = 0; r < 4; ++r) {
        float e = exp2f((p_[fm][r] - m_run) * L2E);
        p_[fm][r] = e;
        s_part += e;
      }

    // pack P fragment: slot j <-> key 16*(j>>2) + 4g + (j&3)  (per-lane, free)
    half8 ap;
#pragma unroll
    for (int j = 0; j < 8; ++j) ap[j] = (h16_t)p_[j >> 2][j & 3];

    // PV: B-frag = two swizzled b64 reads of Vt (keys 4g..4g+3, 16+4g..16+4g+3)
    __builtin_amdgcn_s_setprio(1);
#pragma unroll
    for (int tt = 0; tt < 8; ++tt) {
      int row = 16 * tt + c;
      int sw = (row >> 1) & 3;
      int b1 = (g >> 1), b2 = 2 + (g >> 1);
      int a1 = row * 64 + (((b1 ^ sw)) * 16) + 8 * (g & 1);
      int a2 = row * 64 + (((b2 ^ sw)) * 16) + 8 * (g & 1);
      union { half8 v8; half4v v4[2]; } u;
      u.v4[0] = *reinterpret_cast<const half4v*>(bufV + a1);
      u.v4[1] = *reinterpret_cast<const half4v*>(bufV + a2);
      oacc[tt] = __builtin_amdgcn_mfma_f32_16x16x32_f16(ap, u.v8, oacc[tt], 0, 0, 0);
    }
    __builtin_amdgcn_s_setprio(0);
  }

  // final cross-lane denominator reduce (deferred from the loop)
  float s_run = s_part;
  s_run += __shfl_xor(s_run, 16);
  s_run += __shfl_xor(s_run, 32);

  if (pidx >= 0) {
    // partial: store fp32 O, m, s (consistent w.r.t. m_run reference point)
    float* Od = Opart + (size_t)pidx * 8192;
#pragma unroll
    for (int tt = 0; tt < 8; ++tt)
#pragma unroll
      for (int r = 0; r < 4; ++r)
        Od[(w * 16 + 4 * g + r) * 128 + tt * 16 + c] = oacc[tt][r];
    if (lane < 16) {
      ms[pidx * 128 + w * 16 + c] = m_run;
      ms[pidx * 128 + 64 + w * 16 + c] = s_run;
    }
  } else {
    float sr[4];
#pragma unroll
    for (int r = 0; r < 4; ++r) sr[r] = __shfl(s_run, 4 * g + r);
#pragma unroll
    for (int tt = 0; tt < 8; ++tt)
#pragma unroll
      for (int r = 0; r < 4; ++r) {
        float v = oacc[tt][r] / sr[r];
        ctx[(size_t)(qw + 4 * g + r) * DM + h * HDIM + tt * 16 + c] = (h16_t)v;
      }
  }
}

// ---------------- merge the 2-chunk partials (qb >= 16) ----------------
__global__ void attn_reduce(const float* __restrict__ Opart, const float* __restrict__ ms,
                            h16_t* __restrict__ ctx) {
  const float L2E = 1.4426950408889634f;
  int b = blockIdx.x;          // 256 = 16 heads x 16 qb
  int h = b & 15, qi = b >> 4; // qb = 16 + qi
  int p0 = (h * 32 + qi * 2);
  int tid = threadIdx.x;
  int row = tid >> 2, seg = (tid & 3) * 32;
  float m1 = ms[p0 * 128 + row], s1 = ms[p0 * 128 + 64 + row];
  float m2 = ms[(p0 + 1) * 128 + row], s2 = ms[(p0 + 1) * 128 + 64 + row];
  float M = fmaxf(m1, m2);
  float w1 = exp2f((m1 - M) * L2E), w2 = exp2f((m2 - M) * L2E);
  float inv = 1.0f / (s1 * w1 + s2 * w2);
  const float* O1 = Opart + (size_t)p0 * 8192 + row * 128 + seg;
  const float* O2 = O1 + 8192;
  h16_t* dst = ctx + (size_t)((16 + qi) * 64 + row) * DM + h * HDIM + seg;
#pragma unroll
  for (int j = 0; j < 32; j += 4) {
    float4 a = *reinterpret_cast<const float4*>(O1 + j);
    float4 c2 = *reinterpret_cast<const float4*>(O2 + j);
    dst[j]     = (h16_t)((a.x * w1 + c2.x * w2) * inv);
    dst[j + 1] = (h16_t)((a.y * w1 + c2.y * w2) * inv);
    dst[j + 2] = (h16_t)((a.z * w1 + c2.z * w2) * inv);
    dst[j + 3] = (h16_t)((a.w * w1 + c2.w * w2) * inv);
  }
}

extern "C" void kernel_launch(void* const* d_in, const int* in_sizes, int n_in,
                              void* d_out, int out_size, void* d_ws, size_t ws_size,
                              hipStream_t stream) {
  const float* hs   = (const float*)d_in[0];
  const float* wqkv = (const float*)d_in[1];
  const float* bqkv = (const float*)d_in[2];
  const float* wo   = (const float*)d_in[3];
  const float* bo   = (const float*)d_in[4];
  float* out = (float*)d_out;

  char* ws = (char*)d_ws;
  const size_t MB = 1u << 20;
  h16_t* h_hi    = (h16_t*)(ws + 0 * MB);    // 8 MB  (reused as ctx16 later)
  h16_t* h_lo    = (h16_t*)(ws + 8 * MB);    // 8 MB
  h16_t* qkvT_hi = (h16_t*)(ws + 16 * MB);   // 24 MB [6144][2048]
  h16_t* woT     = (h16_t*)(ws + 56 * MB);   // 8 MB  [2048][2048]
  h16_t* qk_hi   = (h16_t*)(ws + 64 * MB);   // 16 MB [2048][4096]
  h16_t* qk_lo   = (h16_t*)(ws + 88 * MB);   // 16 MB [2048][4096]
  float2* ctab   = (float2*)(ws + 104 * MB); // 1 MB  [2048][64]
  h16_t* vt      = (h16_t*)(ws + 105 * MB);  // 8 MB  [2048 vc][2048 s]
  // attn partials reuse the qkvT region (consumed before attn):
  float* Opart   = (float*)(ws + 16 * MB);   // 16 MB [512][64][128] fp32
  float* msbuf   = (float*)(ws + 32 * MB);   // 256 KB [512][2][64] fp32
  h16_t* ctx16   = h_hi;

  prep_small<<<4608, 256, 0, stream>>>(hs, h_hi, h_lo, ctab);
  transpose_both<<<4096, 256, 0, stream>>>(wqkv, wo, qkvT_hi, woT);

  // q,k columns: 2-product A-split GEMM + fused RoPE (exact fp32 rotate+resplit)
  gemm_qk<<<dim3(32, 16), 256, 0, stream>>>(
      h_hi, h_lo, qkvT_hi, bqkv, qk_hi, qk_lo, ctab);
  // v columns: Vt[vc][s] = WvT * h^T + bias_v (direct transposed output)
  gemm_v<<<dim3(16, 16), 256, 0, stream>>>(
      qkvT_hi + (size_t)4096 * DM, h_hi, bqkv + 4096, vt);

  attn_kernel<<<768, 256, 0, stream>>>(qk_hi, qk_lo, vt, ctx16, Opart, msbuf);
  attn_reduce<<<256, 256, 0, stream>>>(Opart, msbuf, ctx16);

  gemm_oproj<<<dim3(DM / 128, SEQ / 128), 256, 0, stream>>>(ctx16, woT, bo, out);
}

// Round 15
// 235.038 us; speedup vs baseline: 1.0749x; 1.0068x over previous
//
#include <hip/hip_runtime.h>

typedef _Float16 h16_t;
typedef _Float16 half8 __attribute__((ext_vector_type(8)));
typedef _Float16 half4v __attribute__((ext_vector_type(4)));
typedef float f32x4 __attribute__((ext_vector_type(4)));

#define SEQ 2048
#define DM 2048
#define NHEAD 16
#define HDIM 128
#define QKVW 6144
#define QKW 4096

#define GLOAD_LDS(g, l)                                                   \
  __builtin_amdgcn_global_load_lds(                                       \
      (const __attribute__((address_space(1))) void*)(g),                 \
      (__attribute__((address_space(3))) void*)(l), 16, 0, 0)

#define VMCNT(n) asm volatile("s_waitcnt vmcnt(" #n ")" ::: "memory")

// ---- fused prep: hs->(hi,lo) split | cos/sin table | both weight transposes
__global__ void prep_all(const float* __restrict__ hs, h16_t* __restrict__ hi,
                         h16_t* __restrict__ lo, float2* __restrict__ tab,
                         const float* __restrict__ Wqkv, const float* __restrict__ Wo,
                         h16_t* __restrict__ qkvT, h16_t* __restrict__ woT) {
  __shared__ float tile[64][65];
  int p = blockIdx.x;
  if (p < 4096) {
    int i = p * 256 + threadIdx.x;  // SEQ*DM/4 float4s
    float4 v = reinterpret_cast<const float4*>(hs)[i];
    half4v h, l;
    float x;
    x = v.x; h[0] = (h16_t)x; l[0] = (h16_t)(x - (float)h[0]);
    x = v.y; h[1] = (h16_t)x; l[1] = (h16_t)(x - (float)h[1]);
    x = v.z; h[2] = (h16_t)x; l[2] = (h16_t)(x - (float)h[2]);
    x = v.w; h[3] = (h16_t)x; l[3] = (h16_t)(x - (float)h[3]);
    reinterpret_cast<half4v*>(hi)[i] = h;
    reinterpret_cast<half4v*>(lo)[i] = l;
    return;
  }
  if (p < 4608) {
    int idx = (p - 4096) * 256 + threadIdx.x;  // 2048*64
    int s = idx >> 6, i = idx & 63;
    float freq = 1.0f / powf(10000.0f, (float)(2 * i) / 128.0f);
    float ang = (float)s * freq;
    float sn, cs;
    sincosf(ang, &sn, &cs);
    tab[idx] = make_float2(cs, sn);
    return;
  }
  // weight transposes: fp32 W[K][N] -> fp16 Wt[N][K]
  int pp = p - 4608;
  const float* W;
  h16_t* Wt;
  int N, bx, by;
  if (pp < 3072) { W = Wqkv; Wt = qkvT; N = QKVW; bx = pp % 96; by = pp / 96; }
  else           { int q = pp - 3072; W = Wo; Wt = woT; N = DM; bx = q % 32; by = q / 32; }
  int n0 = bx * 64, k0 = by * 64;
  int t = threadIdx.x;  // 256
  int row = t >> 4, c4 = t & 15;
#pragma unroll
  for (int j = 0; j < 4; ++j) {
    float4 v = *reinterpret_cast<const float4*>(
        &W[(size_t)(k0 + j * 16 + row) * N + n0 + c4 * 4]);
    tile[j * 16 + row][c4 * 4 + 0] = v.x;
    tile[j * 16 + row][c4 * 4 + 1] = v.y;
    tile[j * 16 + row][c4 * 4 + 2] = v.z;
    tile[j * 16 + row][c4 * 4 + 3] = v.w;
  }
  __syncthreads();
#pragma unroll
  for (int jj = 0; jj < 2; ++jj) {
    int idx = jj * 256 + t;
    int n = idx >> 3, kc = idx & 7;
    half8 hv;
#pragma unroll
    for (int e = 0; e < 8; ++e) hv[e] = (h16_t)tile[kc * 8 + e][n];
    *reinterpret_cast<half8*>(&Wt[(size_t)(n0 + n) * DM + k0 + kc * 8]) = hv;
  }
}

// ---------------- GEMM body: C[M][N] = A[M][K]*Bt[N][K]^T + bias -----------
// 128x128 tile, BK=32, 4 waves (2x2). R5 schedule (verified):
//   stage(next) | ds_reads | MFMA (setprio) | VMCNT0 | syncthreads.
// ASPLIT: 2-product (Ahi+Alo)*Bhi. OUT: 0 = fp16, 2 = fp32.
// ROPE: in-register rotation + hi/lo re-split. BROW: bias by output row.
template <int ASPLIT, int OUT, int ROPE, int BROW>
__device__ __forceinline__ void gemm_body(
    char* smem,
    const h16_t* __restrict__ Ahi, const h16_t* __restrict__ Alo,
    const h16_t* __restrict__ Bhi,
    const float* __restrict__ bias, void* __restrict__ Cout,
    h16_t* __restrict__ Clo, int brow, int bcol, int ldc, int K, int ldlo,
    int tid, const float2* __restrict__ tab) {
  constexpr int BUF = ASPLIT ? 24576 : 16384;
  const int w = tid >> 6, lane = tid & 63, c = lane & 15, g = lane >> 4;
  const int wr = (w >> 1) * 64, wc = (w & 1) * 64;

  f32x4 acc[4][4] = {};

  auto stage = [&](int bufi, int k0) {
    char* buf = smem + bufi * BUF;
#pragma unroll
    for (int it = 0; it < 2; ++it) {
      int B = it * 256 + tid;
      int row = B >> 2;
      int c8 = (B & 3) ^ ((row >> 1) & 3);
      int loff = it * 4096 + w * 1024;
      GLOAD_LDS(Ahi + (size_t)(brow + row) * K + k0 + c8 * 8, buf + loff);
      GLOAD_LDS(Bhi + (size_t)(bcol + row) * K + k0 + c8 * 8, buf + 8192 + loff);
      if (ASPLIT)
        GLOAD_LDS(Alo + (size_t)(brow + row) * K + k0 + c8 * 8, buf + 16384 + loff);
    }
  };

  int cur = 0;
  stage(0, 0);
  VMCNT(0);
  __syncthreads();

#pragma unroll 1
  for (int k0 = 0; k0 < K; k0 += 32) {
    if (k0 + 32 < K) stage(cur ^ 1, k0 + 32);
    const char* bufc = smem + cur * BUF;
    half8 afh[4], bfh[4], afl[4];
#pragma unroll
    for (int f = 0; f < 4; ++f) {
      int rowa = wr + f * 16 + c;
      int offa = rowa * 64 + ((g ^ ((rowa >> 1) & 3)) * 16);
      int rowb = wc + f * 16 + c;
      int offb = rowb * 64 + ((g ^ ((rowb >> 1) & 3)) * 16);
      afh[f] = *reinterpret_cast<const half8*>(bufc + offa);
      bfh[f] = *reinterpret_cast<const half8*>(bufc + 8192 + offb);
      if (ASPLIT) afl[f] = *reinterpret_cast<const half8*>(bufc + 16384 + offa);
    }
    __builtin_amdgcn_s_setprio(1);
#pragma unroll
    for (int fm = 0; fm < 4; ++fm)
#pragma unroll
      for (int fn = 0; fn < 4; ++fn) {
        acc[fm][fn] = __builtin_amdgcn_mfma_f32_16x16x32_f16(afh[fm], bfh[fn], acc[fm][fn], 0, 0, 0);
        if (ASPLIT)
          acc[fm][fn] = __builtin_amdgcn_mfma_f32_16x16x32_f16(afl[fm], bfh[fn], acc[fm][fn], 0, 0, 0);
      }
    __builtin_amdgcn_s_setprio(0);
    VMCNT(0);
    __syncthreads();
    cur ^= 1;
  }

  const float fac = (ROPE && bcol < 2048) ? 11.31370849898476f : 1.0f;
#pragma unroll
  for (int fm = 0; fm < 4; ++fm)
#pragma unroll
    for (int fn = 0; fn < 4; ++fn) {
      int col = bcol + wc + fn * 16 + c;
      float bv = BROW ? 0.f : bias[col];
#pragma unroll
      for (int r = 0; r < 4; ++r) {
        int row = brow + wr + fm * 16 + 4 * g + r;
        float v = acc[fm][fn][r] + (BROW ? bias[row] : bv);
        if (ROPE) {
          float pv = __shfl_xor(v, 1);
          float2 cc = tab[row * 64 + ((col & 127) >> 1)];
          float y = (col & 1) ? (v * cc.x + pv * cc.y) * fac
                              : (v * cc.x - pv * cc.y) * fac;
          h16_t hv = (h16_t)y;
          ((h16_t*)Cout)[(size_t)row * ldc + col] = hv;
          Clo[(size_t)row * ldlo + col] = (h16_t)(y - (float)hv);
        } else if (OUT == 2) {
          ((float*)Cout)[(size_t)row * ldc + col] = v;
        } else {
          ((h16_t*)Cout)[(size_t)row * ldc + col] = (h16_t)v;
        }
      }
    }
}

// ---------------- q,k columns: 2-product A-split GEMM + fused RoPE ----------
__global__ __launch_bounds__(256) void gemm_qk(
    const h16_t* __restrict__ h_hi, const h16_t* __restrict__ h_lo,
    const h16_t* __restrict__ qkvT_hi, const float* __restrict__ bqkv,
    h16_t* __restrict__ qk_hi, h16_t* __restrict__ qk_lo,
    const float2* __restrict__ tab) {
  __shared__ __align__(16) char smem[49152];
  gemm_body<1, 0, 1, 0>(smem, h_hi, h_lo, qkvT_hi, bqkv, qk_hi, qk_lo,
                        blockIdx.y * 128, blockIdx.x * 128, QKW, DM, QKW,
                        threadIdx.x, tab);
}

// ---------------- v columns -> Vt[vc][s] directly (operands swapped) --------
__global__ __launch_bounds__(256) void gemm_v(
    const h16_t* __restrict__ wvT_hi, const h16_t* __restrict__ h_hi,
    const float* __restrict__ bias_v, h16_t* __restrict__ vt) {
  __shared__ __align__(16) char smem[32768];
  gemm_body<0, 0, 0, 1>(smem, wvT_hi, nullptr, h_hi, bias_v, vt, nullptr,
                        blockIdx.y * 128, blockIdx.x * 128, SEQ, DM, 0,
                        threadIdx.x, nullptr);
}

// ---------------- out-projection GEMM (fp32 out) ----------------
__global__ __launch_bounds__(256) void gemm_oproj(
    const h16_t* __restrict__ A, const h16_t* __restrict__ Bt,
    const float* __restrict__ bias, float* __restrict__ Cout) {
  __shared__ __align__(16) char smem[32768];
  gemm_body<0, 2, 0, 0>(smem, A, nullptr, Bt, bias, Cout, nullptr,
                        blockIdx.y * 128, blockIdx.x * 128, DM, DM, 0,
                        threadIdx.x, nullptr);
}

// ---------------- causal flash attention: QBLK=128, 8 waves, 2-way split-K --
// 512 blocks x 512 thr, 2 blocks/CU (4 waves/SIMD). h = p&15 (XCD-pinned).
//   p<256 : j=p>>4,      keys [0, 64j+64)          -> chunk 0, nt=2j+2
//   p>=256: j=15-(q>>4), keys [64j+64, 128j+128)   -> chunk 1, nt=2j+2
// Per-CU resident pair (j, 15-j): step sum = 36 uniform.
// 2-buffer pipeline (24KB/tile, 48KB LDS), one barrier/step, R5 order.
// Per-wave compute identical to QBLK=64 version (w now 0..7).
__global__ __launch_bounds__(512) void attn_kernel(const h16_t* __restrict__ qhi,
                                                   const h16_t* __restrict__ qlo,
                                                   const h16_t* __restrict__ vt,
                                                   float* __restrict__ Opart,
                                                   float* __restrict__ ms) {
  __shared__ __align__(16) char smem[2 * 24576];
  const int tid = threadIdx.x, w = tid >> 6, lane = tid & 63, c = lane & 15, g = lane >> 4;
  const int p = blockIdx.x;
  const int h = p & 15;
  int j, t0, nt, pidx;
  if (p < 256) { j = p >> 4;          t0 = 0;          nt = 2 * j + 2; pidx = (h * 16 + j) * 2; }
  else         { j = 15 - ((p - 256) >> 4); t0 = 2 * j + 2; nt = 2 * j + 2; pidx = (h * 16 + j) * 2 + 1; }

  const h16_t* Kph = qhi + 2048 + h * HDIM;
  const h16_t* Kpl = qlo + 2048 + h * HDIM;
  const h16_t* Vth = vt + (size_t)h * HDIM * SEQ;
  const float L2E = 1.4426950408889634f;

  const int q0 = j * 128;
  const int qw = q0 + w * 16;

  // stage one KVBLK=32 tile: Khi 8K | Klo 8K | Vt [128d][32key] 8K (3 loads/thr)
  auto stage = [&](int bufi, int t) {
    char* buf = smem + bufi * 24576;
    const int k0 = t * 32;
    int row = tid >> 4;                      // key row 0..31
    int c16 = (tid & 15) ^ (row & 7);
    int loff = w * 1024;
    GLOAD_LDS(Kph + (size_t)(k0 + row) * QKW + c16 * 8, buf + loff);
    GLOAD_LDS(Kpl + (size_t)(k0 + row) * QKW + c16 * 8, buf + 8192 + loff);
    int rv = tid >> 2;                       // d row 0..127
    int c4 = (tid & 3) ^ ((rv >> 1) & 3);
    GLOAD_LDS(Vth + (size_t)rv * SEQ + k0 + c4 * 8, buf + 16384 + loff);
  };

  half8 qfh[4], qfl[4];
#pragma unroll
  for (int kc = 0; kc < 4; ++kc) {
    qfh[kc] = *reinterpret_cast<const half8*>(qhi + (size_t)(qw + c) * QKW + h * HDIM + kc * 32 + g * 8);
    qfl[kc] = *reinterpret_cast<const half8*>(qlo + (size_t)(qw + c) * QKW + h * HDIM + kc * 32 + g * 8);
  }

  f32x4 oacc[8] = {};
  float m_run = -3.0e38f, s_part = 0.f;

  stage(0, t0);

#pragma unroll 1
  for (int i = 0; i < nt; ++i) {
    VMCNT(0);
    __builtin_amdgcn_s_barrier();
    __builtin_amdgcn_sched_barrier(0);
    if (i + 1 < nt) stage((i + 1) & 1, t0 + i + 1);
    __builtin_amdgcn_sched_barrier(0);

    const int k0 = (t0 + i) * 32;
    const char* buf = smem + (i & 1) * 24576;
    const char* bufV = buf + 16384;

    // S^T = K * Q, 3-product split (32 keys x 16 q per wave)
    f32x4 st[2] = {};
    __builtin_amdgcn_s_setprio(1);
#pragma unroll
    for (int kc = 0; kc < 4; ++kc)
#pragma unroll
      for (int fm = 0; fm < 2; ++fm) {
        int row = fm * 16 + c;
        int so = row * 256 + (((4 * kc + g) ^ (row & 7)) * 16);
        half8 kfh = *reinterpret_cast<const half8*>(buf + so);
        half8 kfl = *reinterpret_cast<const half8*>(buf + 8192 + so);
        st[fm] = __builtin_amdgcn_mfma_f32_16x16x32_f16(kfh, qfh[kc], st[fm], 0, 0, 0);
        st[fm] = __builtin_amdgcn_mfma_f32_16x16x32_f16(kfh, qfl[kc], st[fm], 0, 0, 0);
        st[fm] = __builtin_amdgcn_mfma_f32_16x16x32_f16(kfl, qfh[kc], st[fm], 0, 0, 0);
      }
    __builtin_amdgcn_s_setprio(0);

    // causal mask (hoisted) + online softmax (defer-max THR=8, deferred denom)
    float p_[2][4];
    float tmax = -3.0e38f;
    const int qg = qw + c;
    const bool needmask = (k0 + 31 > qw);
#pragma unroll
    for (int fm = 0; fm < 2; ++fm)
#pragma unroll
      for (int r = 0; r < 4; ++r) {
        float sf = st[fm][r];
        if (needmask) {
          int key = k0 + fm * 16 + 4 * g + r;
          sf = (key > qg) ? -3.0e38f : sf;
        }
        p_[fm][r] = sf;
        tmax = fmaxf(tmax, sf);
      }
    tmax = fmaxf(tmax, __shfl_xor(tmax, 16));
    tmax = fmaxf(tmax, __shfl_xor(tmax, 32));
    if (!__all(tmax - m_run <= 8.0f)) {
      float m_new = fmaxf(m_run, tmax);
      float alpha = exp2f((m_run - m_new) * L2E);
      float ar[4];
#pragma unroll
      for (int r = 0; r < 4; ++r) ar[r] = __shfl(alpha, 4 * g + r);
#pragma unroll
      for (int tt = 0; tt < 8; ++tt)
#pragma unroll
        for (int r = 0; r < 4; ++r) oacc[tt][r] *= ar[r];
      s_part *= alpha;
      m_run = m_new;
    }
#pragma unroll
    for (int fm = 0; fm < 2; ++fm)
#pragma unroll
      for (int r = 0; r < 4; ++r) {
        float e = exp2f((p_[fm][r] - m_run) * L2E);
        p_[fm][r] = e;
        s_part += e;
      }

    // pack P fragment: slot jj <-> key 16*(jj>>2) + 4g + (jj&3) (per-lane)
    half8 ap;
#pragma unroll
    for (int jj = 0; jj < 8; ++jj) ap[jj] = (h16_t)p_[jj >> 2][jj & 3];

    // PV: B-frag = two swizzled b64 reads of Vt
    __builtin_amdgcn_s_setprio(1);
#pragma unroll
    for (int tt = 0; tt < 8; ++tt) {
      int row = 16 * tt + c;
      int sw = (row >> 1) & 3;
      int b1 = (g >> 1), b2 = 2 + (g >> 1);
      int a1 = row * 64 + (((b1 ^ sw)) * 16) + 8 * (g & 1);
      int a2 = row * 64 + (((b2 ^ sw)) * 16) + 8 * (g & 1);
      union { half8 v8; half4v v4[2]; } u;
      u.v4[0] = *reinterpret_cast<const half4v*>(bufV + a1);
      u.v4[1] = *reinterpret_cast<const half4v*>(bufV + a2);
      oacc[tt] = __builtin_amdgcn_mfma_f32_16x16x32_f16(ap, u.v8, oacc[tt], 0, 0, 0);
    }
    __builtin_amdgcn_s_setprio(0);
  }

  // final cross-lane denominator reduce (deferred from the loop)
  float s_run = s_part;
  s_run += __shfl_xor(s_run, 16);
  s_run += __shfl_xor(s_run, 32);

  // all blocks store fp32 partials {O, m, s}
  float* Od = Opart + (size_t)pidx * 16384;
#pragma unroll
  for (int tt = 0; tt < 8; ++tt)
#pragma unroll
    for (int r = 0; r < 4; ++r)
      Od[(w * 16 + 4 * g + r) * 128 + tt * 16 + c] = oacc[tt][r];
  if (lane < 16) {
    ms[pidx * 256 + w * 16 + c] = m_run;
    ms[pidx * 256 + 128 + w * 16 + c] = s_run;
  }
}

// ---------------- merge the 2-chunk partials (all rows) ----------------
__global__ void attn_reduce(const float* __restrict__ Opart, const float* __restrict__ ms,
                            h16_t* __restrict__ ctx) {
  const float L2E = 1.4426950408889634f;
  int b = blockIdx.x;          // 256 = 16 heads x 16 j
  int h = b & 15, j = b >> 4;
  int p0 = (h * 16 + j) * 2;
  int tid = threadIdx.x;
#pragma unroll
  for (int rr = 0; rr < 2; ++rr) {
    int row = rr * 64 + (tid >> 2), seg = (tid & 3) * 32;
    float m1 = ms[p0 * 256 + row], s1 = ms[p0 * 256 + 128 + row];
    float m2 = ms[(p0 + 1) * 256 + row], s2 = ms[(p0 + 1) * 256 + 128 + row];
    float M = fmaxf(m1, m2);
    float w1 = exp2f((m1 - M) * L2E), w2 = exp2f((m2 - M) * L2E);
    float inv = 1.0f / (s1 * w1 + s2 * w2);
    const float* O1 = Opart + (size_t)p0 * 16384 + row * 128 + seg;
    const float* O2 = O1 + 16384;
    h16_t* dst = ctx + (size_t)(j * 128 + row) * DM + h * HDIM + seg;
#pragma unroll
    for (int jj = 0; jj < 32; jj += 4) {
      float4 a = *reinterpret_cast<const float4*>(O1 + jj);
      float4 c2 = *reinterpret_cast<const float4*>(O2 + jj);
      dst[jj]     = (h16_t)((a.x * w1 + c2.x * w2) * inv);
      dst[jj + 1] = (h16_t)((a.y * w1 + c2.y * w2) * inv);
      dst[jj + 2] = (h16_t)((a.z * w1 + c2.z * w2) * inv);
      dst[jj + 3] = (h16_t)((a.w * w1 + c2.w * w2) * inv);
    }
  }
}

extern "C" void kernel_launch(void* const* d_in, const int* in_sizes, int n_in,
                              void* d_out, int out_size, void* d_ws, size_t ws_size,
                              hipStream_t stream) {
  const float* hs   = (const float*)d_in[0];
  const float* wqkv = (const float*)d_in[1];
  const float* bqkv = (const float*)d_in[2];
  const float* wo   = (const float*)d_in[3];
  const float* bo   = (const float*)d_in[4];
  float* out = (float*)d_out;

  char* ws = (char*)d_ws;
  const size_t MB = 1u << 20;
  h16_t* h_hi    = (h16_t*)(ws + 0 * MB);    // 8 MB  (reused as ctx16 later)
  h16_t* h_lo    = (h16_t*)(ws + 8 * MB);    // 8 MB
  h16_t* qkvT_hi = (h16_t*)(ws + 16 * MB);   // 24 MB [6144][2048]
  h16_t* woT     = (h16_t*)(ws + 56 * MB);   // 8 MB  [2048][2048]
  h16_t* qk_hi   = (h16_t*)(ws + 64 * MB);   // 16 MB [2048][4096]
  h16_t* qk_lo   = (h16_t*)(ws + 88 * MB);   // 16 MB [2048][4096]
  float2* ctab   = (float2*)(ws + 104 * MB); // 1 MB  [2048][64]
  h16_t* vt      = (h16_t*)(ws + 105 * MB);  // 8 MB  [2048 vc][2048 s]
  // attn partials reuse the qkvT region (consumed before attn):
  float* Opart   = (float*)(ws + 16 * MB);   // 32 MB [512][128][128] fp32
  float* msbuf   = (float*)(ws + 48 * MB);   // 512 KB [512][2][128] fp32
  h16_t* ctx16   = h_hi;

  prep_all<<<8704, 256, 0, stream>>>(hs, h_hi, h_lo, ctab, wqkv, wo, qkvT_hi, woT);

  // q,k columns: 2-product A-split GEMM + fused RoPE (exact fp32 rotate+resplit)
  gemm_qk<<<dim3(32, 16), 256, 0, stream>>>(
      h_hi, h_lo, qkvT_hi, bqkv, qk_hi, qk_lo, ctab);
  // v columns: Vt[vc][s] = WvT * h^T + bias_v (direct transposed output)
  gemm_v<<<dim3(16, 16), 256, 0, stream>>>(
      qkvT_hi + (size_t)4096 * DM, h_hi, bqkv + 4096, vt);

  attn_kernel<<<512, 512, 0, stream>>>(qk_hi, qk_lo, vt, Opart, msbuf);
  attn_reduce<<<256, 256, 0, stream>>>(Opart, msbuf, ctx16);

  gemm_oproj<<<dim3(DM / 128, SEQ / 128), 256, 0, stream>>>(ctx16, woT, bo, out);
}